// Round 24
// baseline (131.007 us; speedup 1.0000x reference)
//
#include <hip/hip_runtime.h>
#include <hip/hip_fp16.h>

#define Bn    8
#define Cn    64
#define Hn    128
#define Wn    128
#define KK    9
#define OffC  18
#define NG    4
#define Cg    16
#define HW    (Hn*Wn)

#define OFFS_ELEMS (Bn*OffC*HW)      // float count (layout: [b][t][HW] float2)
#define WAO_ELEMS  (KK*4*64*8)
#define WAD_ELEMS  (NG*KK*64*8)

// deform tile geometry: 4 rows (halo +-2), 64-col half (x-halo +-2), plane-major
#define ROWS  4
#define TR    8
#define XT    68                     // staged real cols: xb-2 .. xb+65
#define TSTRX 70                     // padded col stride
#define PLANE (TR*TSTRX)             // 560 words per channel-pair plane
#define TILE_WX (8*PLANE)            // 4480 words
#define TILE_PADX 72                 // overrun pad (zeroed)

typedef __attribute__((ext_vector_type(8)))  short short8v;
typedef __attribute__((ext_vector_type(8)))  _Float16 half8v;
typedef __attribute__((ext_vector_type(4)))  unsigned int uint4v;
typedef __attribute__((ext_vector_type(16))) float f32x16;

__device__ __forceinline__ unsigned int rne16(float f) {
    unsigned int u = __float_as_uint(f);
    return (u + 0x7FFFu + ((u >> 16) & 1u)) >> 16;   // bf16 RNE
}
// pure bit-math bf16 pack — REQUIRED in the offset conv (R12/R22: any other pack
// variant collapses its load pipelining 3x).
__device__ __forceinline__ unsigned int pack2(float lo, float hi) {
    const unsigned int a = rne16(lo);
    unsigned int b = __float_as_uint(hi);
    b = (b + 0x7FFFu + ((b >> 16) & 1u)) & 0xFFFF0000u;
    return b | a;
}

// ---------- Kernel 0: prep MFMA A-fragment tables (wAo bf16, wAd f16) ----------
__global__ __launch_bounds__(256) void prep_w_kernel(
    const float* __restrict__ offw, const float* __restrict__ dw,
    unsigned short* __restrict__ wAo, unsigned short* __restrict__ wAd)
{
    const int tid = blockIdx.x * 256 + threadIdx.x;
    const int nth = gridDim.x * 256;
    for (int i = tid; i < WAO_ELEMS; i += nth) {
        const int e    = i & 7;
        const int lane = (i >> 3) & 63;
        const int q    = (i >> 9) & 3;
        const int t    = i >> 11;
        const int o    = lane & 31;
        const int c    = q * 16 + 8 * (lane >> 5) + e;
        const float v  = (o < OffC) ? offw[(o * Cn + c) * KK + t] : 0.f;
        wAo[i] = (unsigned short)rne16(v);
    }
    for (int i = tid; i < WAD_ELEMS; i += nth) {
        const int e    = i & 7;
        const int lane = (i >> 3) & 63;
        const int t    = (i >> 9) % KK;
        const int g    = i / (512 * KK);
        const int o    = lane & 31;
        const int c    = 8 * (lane >> 5) + e;
        const float v  = (o < Cg) ? dw[((g * Cg + o) * Cg + c) * KK + t] : 0.f;
        wAd[i] = __half_as_ushort(__float2half_rn(v));
    }
}

// ---------- Kernel 1: offset conv via bf16 MFMA + paired float2 store (R23 proven) ----------
__global__ __launch_bounds__(256, 4) void offset_conv_kernel(
    const float* __restrict__ x, const unsigned short* __restrict__ wAo,
    const float* __restrict__ bias, float2* __restrict__ offs2)
{
    const int tid  = threadIdx.x;
    const int wv   = tid >> 6;
    const int lane = tid & 63;
    const int p    = lane & 31;
    const int h    = lane >> 5;
    const int b    = blockIdx.y;
    const int r    = blockIdx.x;
    const int col  = wv * 32 + p;

    const float* xb = x + (size_t)b * Cn * HW;

    f32x16 acc;
#pragma unroll
    for (int i = 0; i < 16; ++i) acc[i] = 0.f;

#pragma unroll 1
    for (int q = 0; q < 4; ++q) {
        unsigned int win[4][3][3];
#pragma unroll
        for (int i = 0; i < 4; ++i) {
            const float* xc0 = xb + (size_t)(q * 16 + 8 * h + 2 * i) * HW;
            const float* xc1 = xc0 + HW;
#pragma unroll
            for (int ky = 0; ky < 3; ++ky) {
                const int  y   = r - 1 + ky;
                const bool yok = ((unsigned)y < (unsigned)Hn);
#pragma unroll
                for (int kx = 0; kx < 3; ++kx) {
                    const int  xx = col - 1 + kx;
                    const bool ok = yok && ((unsigned)xx < (unsigned)Wn);
                    const float f0 = ok ? xc0[y * Wn + xx] : 0.f;
                    const float f1 = ok ? xc1[y * Wn + xx] : 0.f;
                    win[i][ky][kx] = pack2(f0, f1);
                }
            }
        }
#pragma unroll
        for (int t = 0; t < KK; ++t) {
            uint4v bw;
            bw[0] = win[0][t / 3][t % 3];
            bw[1] = win[1][t / 3][t % 3];
            bw[2] = win[2][t / 3][t % 3];
            bw[3] = win[3][t / 3][t % 3];
            const short8v bfrag = __builtin_bit_cast(short8v, bw);
            const short8v afrag = *(const short8v*)(wAo + (size_t)(t * 4 + q) * 512 + lane * 8);
            acc = __builtin_amdgcn_mfma_f32_32x32x16_bf16(afrag, bfrag, acc, 0, 0, 0);
        }
    }

    float2* ob2 = offs2 + ((size_t)b * KK) * HW + r * Wn + col;
#pragma unroll
    for (int reg = 0; reg < 16; reg += 2) {
        const int o = (reg & 3) + 8 * (reg >> 2) + 4 * h;   // even
        if (o < OffC) {
            const int t = o >> 1;
            float2 v;
            v.x = acc[reg]     + bias[o];
            v.y = acc[reg + 1] + bias[o + 1];
            ob2[(size_t)t * HW] = v;
        }
    }
}

// ---------- slow-path tap state (weight-swap boundary math + x-bounds) ----------
struct TapS {
    int   base;
    int   gr0, gr1, gc0, gc1;
    float m00, m01, m10, m11;
    bool  cond;
};

__device__ __forceinline__ TapS tap_setup(
    int r, int col, int ky, int kx, float offy, float offx,
    int ylo, int yhi, int xlo0, int xloR, int xhiR)
{
    TapS s;
    const float pyf = (float)(r - 1 + ky) + offy;
    const float pxf = (float)(col - 1 + kx) + offx;
    const float y0f = floorf(pyf), x0f = floorf(pxf);
    const float wy = pyf - y0f, wx = pxf - x0f;
    const int y0 = (int)y0f, x0 = (int)x0f;
    const int by = min(max(y0, 0), Hn - 1);
    const int bx = min(max(x0, 0), Wn - 1);
    const float w0p = (by == y0) ? (1.f - wy) : ((by == y0 + 1) ? wy : 0.f);
    const float w1p = (by == y0 && y0 + 1 <= Hn - 1) ? wy : 0.f;
    const float v0p = (bx == x0) ? (1.f - wx) : ((bx == x0 + 1) ? wx : 0.f);
    const float v1p = (bx == x0 && x0 + 1 <= Wn - 1) ? wx : 0.f;
    s.m00 = w0p * v0p; s.m01 = w0p * v1p;
    s.m10 = w1p * v0p; s.m11 = w1p * v1p;
    s.base = (by - ylo) * TSTRX + (bx - xlo0);
    s.cond = (by >= ylo) && (min(by + 1, Hn - 1) <= yhi)
          && (bx >= xloR) && (min(bx + 1, Wn - 1) <= xhiR);
    s.gr0 = by; s.gr1 = min(by + 1, Hn - 1);
    s.gc0 = bx; s.gc1 = min(bx + 1, Wn - 1);
    return s;
}

__device__ __forceinline__ uint4v tap_sample(
    const TapS& s, int h, const __half2* __restrict__ tile,
    const float* __restrict__ sg)
{
    uint4v bw;
    if (s.cond) {
        const __half2 m00h = __float2half2_rn(s.m00);
        const __half2 m01h = __float2half2_rn(s.m01);
        const __half2 m10h = __float2half2_rn(s.m10);
        const __half2 m11h = __float2half2_rn(s.m11);
#pragma unroll
        for (int wi = 0; wi < 4; ++wi) {
            const __half2* tw = tile + (4 * h + wi) * PLANE;
            __half2 a = __hmul2(tw[s.base], m00h);
            a = __hfma2(tw[s.base + 1], m01h, a);
            a = __hfma2(tw[s.base + TSTRX], m10h, a);
            a = __hfma2(tw[s.base + TSTRX + 1], m11h, a);
            bw[wi] = __builtin_bit_cast(unsigned int, a);
        }
    } else {
        const int ia0 = s.gr0 * Wn + s.gc0, ia1 = s.gr0 * Wn + s.gc1;
        const int ia2 = s.gr1 * Wn + s.gc0, ia3 = s.gr1 * Wn + s.gc1;
#pragma unroll
        for (int wi = 0; wi < 4; ++wi) {
            const float* sc0 = sg + (size_t)(8 * h + 2 * wi) * HW;
            const float* sc1 = sc0 + HW;
            const float v0 = sc0[ia0] * s.m00 + sc0[ia1] * s.m01 + sc0[ia2] * s.m10 + sc0[ia3] * s.m11;
            const float v1 = sc1[ia0] * s.m00 + sc1[ia1] * s.m01 + sc1[ia2] * s.m10 + sc1[ia3] * s.m11;
            bw[wi] = __builtin_bit_cast(unsigned int, __floats2half2_rn(v0, v1));
        }
    }
    return bw;
}

// one chunk, one tap: wave-uniform fast path when ALL lanes interior (identical math)
__device__ __forceinline__ uint4v chunk_tap(
    int r, int col, int ky, int kx, float oy, float ox,
    int ylo, int yhi, int xlo0, int xloR, int xhiR, int h,
    const __half2* __restrict__ tile, const float* __restrict__ sg)
{
    const float pyf = (float)(r - 1 + ky) + oy;
    const float pxf = (float)(col - 1 + kx) + ox;
    const float y0f = floorf(pyf), x0f = floorf(pxf);
    const float wy = pyf - y0f, wx = pxf - x0f;
    const int y0 = (int)y0f, x0 = (int)x0f;
    const bool interior = (y0 >= ylo) & (y0 + 1 <= yhi) & (x0 >= xloR) & (x0 + 1 <= xhiR);

    uint4v bw;
    if (__all(interior)) {
        const float iy = 1.f - wy, ix = 1.f - wx;
        const __half2 m00h = __float2half2_rn(iy * ix);
        const __half2 m01h = __float2half2_rn(iy * wx);
        const __half2 m10h = __float2half2_rn(wy * ix);
        const __half2 m11h = __float2half2_rn(wy * wx);
        const int base = (y0 - ylo) * TSTRX + (x0 - xlo0);
#pragma unroll
        for (int wi = 0; wi < 4; ++wi) {
            const __half2* tw = tile + (4 * h + wi) * PLANE;
            __half2 a = __hmul2(tw[base], m00h);
            a = __hfma2(tw[base + 1], m01h, a);
            a = __hfma2(tw[base + TSTRX], m10h, a);
            a = __hfma2(tw[base + TSTRX + 1], m11h, a);
            bw[wi] = __builtin_bit_cast(unsigned int, a);
        }
    } else {
        const TapS s = tap_setup(r, col, ky, kx, oy, ox, ylo, yhi, xlo0, xloR, xhiR);
        bw = tap_sample(s, h, tile, sg);
    }
    return bw;
}

// ---------- Kernel 2: deform conv — 256-thr blocks, (b,g,4rows,64-col half) ----------
__global__ __launch_bounds__(256, 8) void deform_kernel(
    const float* __restrict__ skip, const float2* __restrict__ offs2,
    const unsigned short* __restrict__ wA, float* __restrict__ out)
{
    __shared__ __half2 tile[TILE_WX + TILE_PADX];   // 18208 B -> 8 blocks/CU

    const int tid = threadIdx.x;
    const int yb  = blockIdx.y;
    const int xh  = yb & 1;
    const int g   = (yb >> 1) & 3;
    const int b   = yb >> 3;
    const int r0  = blockIdx.x * ROWS;
    const int ylo = max(0, r0 - 2);
    const int yhi = min(Hn - 1, r0 + ROWS + 1);
    const int xb  = xh * 64;
    const int xlo0 = xb - 2;
    const int xloR = max(0, xlo0);
    const int xhiR = min(Wn - 1, xb + 65);

    const float* sg = skip + (size_t)(b * Cn + g * Cg) * HW;

    // stage: tile[(4h'+w)*PLANE + ty*TSTRX + j] = half2(ch 2w, 2w+1) at (ylo+ty, xlo0+j)
    // unstaged words (pad cols, out-of-range y/x) ZEROED (weight-0 reads touch them)
    for (int i = tid; i < TILE_WX; i += 256) {
        const int w  = i / PLANE;
        const int re = i % PLANE;
        const int ty = re / TSTRX;
        const int j  = re % TSTRX;
        const int y  = ylo + ty;
        const int x  = xlo0 + j;
        __half2 v = __floats2half2_rn(0.f, 0.f);
        if (j < XT && y <= yhi && x >= 0 && x < Wn) {
            const float f0 = sg[(2 * w)     * HW + y * Wn + x];
            const float f1 = sg[(2 * w + 1) * HW + y * Wn + x];
            v = __floats2half2_rn(f0, f1);
        }
        tile[i] = v;
    }
    for (int i = TILE_WX + tid; i < TILE_WX + TILE_PADX; i += 256)
        tile[i] = __floats2half2_rn(0.f, 0.f);
    __syncthreads();

    const int wv   = tid >> 6;          // 0..3 -> row
    const int lane = tid & 63;
    const int p    = lane & 31;
    const int h    = lane >> 5;
    const int r    = r0 + wv;
    const int colA = xb + p;
    const int colB = colA + 32;

    const unsigned short* wAg = wA + (size_t)g * (KK * 512) + lane * 8;
    const float2* offpA = offs2 + (size_t)b * KK * HW + r * Wn + colA;
    const float2* offpB = offpA + 32;

    f32x16 accA, accB;
#pragma unroll
    for (int i = 0; i < 16; ++i) { accA[i] = 0.f; accB[i] = 0.f; }

#pragma unroll
    for (int t = 0; t < KK; ++t) {
        const int ky = t / 3, kx = t % 3;
        const float2 oA = offpA[(size_t)t * HW];   // one 8B load: (y,x)
        const float2 oB = offpB[(size_t)t * HW];

        const uint4v bwA = chunk_tap(r, colA, ky, kx, oA.x, oA.y,
                                     ylo, yhi, xlo0, xloR, xhiR, h, tile, sg);
        const uint4v bwB = chunk_tap(r, colB, ky, kx, oB.x, oB.y,
                                     ylo, yhi, xlo0, xloR, xhiR, h, tile, sg);

        const half8v afrag = *(const half8v*)(wAg + t * 512);
        accA = __builtin_amdgcn_mfma_f32_32x32x16_f16(afrag, __builtin_bit_cast(half8v, bwA), accA, 0, 0, 0);
        accB = __builtin_amdgcn_mfma_f32_32x32x16_f16(afrag, __builtin_bit_cast(half8v, bwB), accB, 0, 0, 0);
    }

    float* obA = out + (size_t)(b * Cn + g * Cg) * HW + r * Wn + colA;
#pragma unroll
    for (int reg = 0; reg < 8; ++reg) {
        const int o = (reg & 3) + 8 * (reg >> 2) + 4 * h;
        obA[o * HW]      = accA[reg];
        obA[o * HW + 32] = accB[reg];
    }
}

extern "C" void kernel_launch(void* const* d_in, const int* in_sizes, int n_in,
                              void* d_out, int out_size, void* d_ws, size_t ws_size,
                              hipStream_t stream) {
    const float* x        = (const float*)d_in[0];
    const float* skip     = (const float*)d_in[1];
    const float* offset_w = (const float*)d_in[2];
    const float* offset_b = (const float*)d_in[3];
    const float* deform_w = (const float*)d_in[4];
    float* out  = (float*)d_out;

    float2* offs2 = (float2*)d_ws;                                // 9.44 MB ([b][t][HW] pairs)
    unsigned short* wAo = (unsigned short*)((float*)d_ws + OFFS_ELEMS);  // 36.9 KB (bf16)
    unsigned short* wAd = wAo + WAO_ELEMS;                        // 36.9 KB (f16)

    hipLaunchKernelGGL(prep_w_kernel, dim3(8), dim3(256), 0, stream,
                       offset_w, deform_w, wAo, wAd);
    hipLaunchKernelGGL(offset_conv_kernel, dim3(Hn, Bn), dim3(256), 0, stream,
                       x, wAo, offset_b, offs2);
    hipLaunchKernelGGL(deform_kernel, dim3(Hn / ROWS, Bn * NG * 2), dim3(256), 0, stream,
                       skip, offs2, wAd, out);
}

// Round 25
// 75.728 us; speedup vs baseline: 1.7300x; 1.7300x over previous
//
#include <hip/hip_runtime.h>
#include <hip/hip_fp16.h>

#define Bn    8
#define Cn    64
#define Hn    128
#define Wn    128
#define KK    9
#define OffC  18
#define NG    4
#define Cg    16
#define HW    (Hn*Wn)

#define OFFS_ELEMS (Bn*OffC*HW)      // float count (layout: [b][t][HW] float2)
#define WAO_ELEMS  (KK*4*64*8)
#define WAD_ELEMS  (NG*KK*64*8)

// deform tile geometry: 4 output rows, halo 2 up / 2 down (proven, plane-major)
#define ROWS  4
#define TR    8
#define NW    8
#define TSTR  132
#define TILE_W (NW*TR*TSTR)
#define TILE_PAD (TSTR + 4)

typedef __attribute__((ext_vector_type(8)))  short short8v;
typedef __attribute__((ext_vector_type(8)))  _Float16 half8v;
typedef __attribute__((ext_vector_type(4)))  unsigned int uint4v;
typedef __attribute__((ext_vector_type(16))) float f32x16;

__device__ __forceinline__ unsigned int rne16(float f) {
    unsigned int u = __float_as_uint(f);
    return (u + 0x7FFFu + ((u >> 16) & 1u)) >> 16;   // bf16 RNE
}
// pure bit-math bf16 pack — REQUIRED in the offset conv: every other pack variant
// (asm cvt_pk R12, f16 intrinsic R22) collapsed its load pipelining 3x.
__device__ __forceinline__ unsigned int pack2(float lo, float hi) {
    const unsigned int a = rne16(lo);
    unsigned int b = __float_as_uint(hi);
    b = (b + 0x7FFFu + ((b >> 16) & 1u)) & 0xFFFF0000u;
    return b | a;
}

// ---------- Kernel 0: prep MFMA A-fragment tables (wAo bf16, wAd f16) ----------
__global__ __launch_bounds__(256) void prep_w_kernel(
    const float* __restrict__ offw, const float* __restrict__ dw,
    unsigned short* __restrict__ wAo, unsigned short* __restrict__ wAd)
{
    const int tid = blockIdx.x * 256 + threadIdx.x;
    const int nth = gridDim.x * 256;
    for (int i = tid; i < WAO_ELEMS; i += nth) {
        const int e    = i & 7;
        const int lane = (i >> 3) & 63;
        const int q    = (i >> 9) & 3;
        const int t    = i >> 11;
        const int o    = lane & 31;
        const int c    = q * 16 + 8 * (lane >> 5) + e;
        const float v  = (o < OffC) ? offw[(o * Cn + c) * KK + t] : 0.f;
        wAo[i] = (unsigned short)rne16(v);
    }
    for (int i = tid; i < WAD_ELEMS; i += nth) {
        const int e    = i & 7;
        const int lane = (i >> 3) & 63;
        const int t    = (i >> 9) % KK;
        const int g    = i / (512 * KK);
        const int o    = lane & 31;
        const int c    = 8 * (lane >> 5) + e;
        const float v  = (o < Cg) ? dw[((g * Cg + o) * Cg + c) * KK + t] : 0.f;
        wAd[i] = __half_as_ushort(__float2half_rn(v));
    }
}

// ---------- Kernel 1: offset conv via bf16 MFMA (R9/R20 proven) + PAIRED store ----------
// Store layout: offs is [b][t][H][W] of float2 (y,x) — even regs hold o=2t, odd o=2t+1.
__global__ __launch_bounds__(256, 4) void offset_conv_kernel(
    const float* __restrict__ x, const unsigned short* __restrict__ wAo,
    const float* __restrict__ bias, float2* __restrict__ offs2)
{
    const int tid  = threadIdx.x;
    const int wv   = tid >> 6;
    const int lane = tid & 63;
    const int p    = lane & 31;
    const int h    = lane >> 5;
    const int b    = blockIdx.y;
    const int r    = blockIdx.x;
    const int col  = wv * 32 + p;

    const float* xb = x + (size_t)b * Cn * HW;

    f32x16 acc;
#pragma unroll
    for (int i = 0; i < 16; ++i) acc[i] = 0.f;

#pragma unroll 1
    for (int q = 0; q < 4; ++q) {
        unsigned int win[4][3][3];
#pragma unroll
        for (int i = 0; i < 4; ++i) {
            const float* xc0 = xb + (size_t)(q * 16 + 8 * h + 2 * i) * HW;
            const float* xc1 = xc0 + HW;
#pragma unroll
            for (int ky = 0; ky < 3; ++ky) {
                const int  y   = r - 1 + ky;
                const bool yok = ((unsigned)y < (unsigned)Hn);
#pragma unroll
                for (int kx = 0; kx < 3; ++kx) {
                    const int  xx = col - 1 + kx;
                    const bool ok = yok && ((unsigned)xx < (unsigned)Wn);
                    const float f0 = ok ? xc0[y * Wn + xx] : 0.f;
                    const float f1 = ok ? xc1[y * Wn + xx] : 0.f;
                    win[i][ky][kx] = pack2(f0, f1);
                }
            }
        }
#pragma unroll
        for (int t = 0; t < KK; ++t) {
            uint4v bw;
            bw[0] = win[0][t / 3][t % 3];
            bw[1] = win[1][t / 3][t % 3];
            bw[2] = win[2][t / 3][t % 3];
            bw[3] = win[3][t / 3][t % 3];
            const short8v bfrag = __builtin_bit_cast(short8v, bw);
            const short8v afrag = *(const short8v*)(wAo + (size_t)(t * 4 + q) * 512 + lane * 8);
            acc = __builtin_amdgcn_mfma_f32_32x32x16_bf16(afrag, bfrag, acc, 0, 0, 0);
        }
    }

    float2* ob2 = offs2 + ((size_t)b * KK) * HW + r * Wn + col;
#pragma unroll
    for (int reg = 0; reg < 16; reg += 2) {
        const int o = (reg & 3) + 8 * (reg >> 2) + 4 * h;   // even
        if (o < OffC) {
            const int t = o >> 1;
            float2 v;
            v.x = acc[reg]     + bias[o];
            v.y = acc[reg + 1] + bias[o + 1];
            ob2[(size_t)t * HW] = v;
        }
    }
}

// ---------- slow-path tap state (R18-proven weight-swap boundary math) ----------
struct TapS {
    int   base;
    int   gr0, gr1, gc0, gc1;
    float m00, m01, m10, m11;
    bool  cond;
};

__device__ __forceinline__ TapS tap_setup(
    int r, int col, int ky, int kx, float offy, float offx, int ylo, int yhi)
{
    TapS s;
    const float pyf = (float)(r - 1 + ky) + offy;
    const float pxf = (float)(col - 1 + kx) + offx;
    const float y0f = floorf(pyf), x0f = floorf(pxf);
    const float wy = pyf - y0f, wx = pxf - x0f;
    const int y0 = (int)y0f, x0 = (int)x0f;
    const int by = min(max(y0, 0), Hn - 1);
    const int bx = min(max(x0, 0), Wn - 1);
    const float w0p = (by == y0) ? (1.f - wy) : ((by == y0 + 1) ? wy : 0.f);
    const float w1p = (by == y0 && y0 + 1 <= Hn - 1) ? wy : 0.f;
    const float v0p = (bx == x0) ? (1.f - wx) : ((bx == x0 + 1) ? wx : 0.f);
    const float v1p = (bx == x0 && x0 + 1 <= Wn - 1) ? wx : 0.f;
    s.m00 = w0p * v0p; s.m01 = w0p * v1p;
    s.m10 = w1p * v0p; s.m11 = w1p * v1p;
    s.base = (by - ylo) * TSTR + bx;
    s.cond = (by >= ylo) && (min(by + 1, Hn - 1) <= yhi);
    s.gr0 = by; s.gr1 = min(by + 1, Hn - 1);
    s.gc0 = bx; s.gc1 = min(bx + 1, Wn - 1);
    return s;
}

__device__ __forceinline__ uint4v tap_sample(
    const TapS& s, int h, const __half2* __restrict__ tile,
    const float* __restrict__ sg)
{
    uint4v bw;
    if (s.cond) {
        const __half2 m00h = __float2half2_rn(s.m00);
        const __half2 m01h = __float2half2_rn(s.m01);
        const __half2 m10h = __float2half2_rn(s.m10);
        const __half2 m11h = __float2half2_rn(s.m11);
#pragma unroll
        for (int wi = 0; wi < 4; ++wi) {
            const __half2* tw = tile + ((4 * h + wi) * TR) * TSTR;
            __half2 a = __hmul2(tw[s.base], m00h);
            a = __hfma2(tw[s.base + 1], m01h, a);
            a = __hfma2(tw[s.base + TSTR], m10h, a);
            a = __hfma2(tw[s.base + TSTR + 1], m11h, a);
            bw[wi] = __builtin_bit_cast(unsigned int, a);
        }
    } else {
        const int ia0 = s.gr0 * Wn + s.gc0, ia1 = s.gr0 * Wn + s.gc1;
        const int ia2 = s.gr1 * Wn + s.gc0, ia3 = s.gr1 * Wn + s.gc1;
#pragma unroll
        for (int wi = 0; wi < 4; ++wi) {
            const float* sc0 = sg + (size_t)(8 * h + 2 * wi) * HW;
            const float* sc1 = sc0 + HW;
            const float v0 = sc0[ia0] * s.m00 + sc0[ia1] * s.m01 + sc0[ia2] * s.m10 + sc0[ia3] * s.m11;
            const float v1 = sc1[ia0] * s.m00 + sc1[ia1] * s.m01 + sc1[ia2] * s.m10 + sc1[ia3] * s.m11;
            bw[wi] = __builtin_bit_cast(unsigned int, __floats2half2_rn(v0, v1));
        }
    }
    return bw;
}

// one chunk, one tap: wave-uniform fast path when ALL lanes interior (identical math)
__device__ __forceinline__ uint4v chunk_tap(
    int r, int col, int ky, int kx, float oy, float ox, int ylo, int yhi, int h,
    const __half2* __restrict__ tile, const float* __restrict__ sg)
{
    const float pyf = (float)(r - 1 + ky) + oy;
    const float pxf = (float)(col - 1 + kx) + ox;
    const float y0f = floorf(pyf), x0f = floorf(pxf);
    const float wy = pyf - y0f, wx = pxf - x0f;
    const int y0 = (int)y0f, x0 = (int)x0f;
    const bool interior = (y0 >= ylo) & (y0 + 1 <= yhi) & (x0 >= 0) & (x0 + 1 <= Wn - 1);

    uint4v bw;
    if (__all(interior)) {
        const float iy = 1.f - wy, ix = 1.f - wx;
        const __half2 m00h = __float2half2_rn(iy * ix);
        const __half2 m01h = __float2half2_rn(iy * wx);
        const __half2 m10h = __float2half2_rn(wy * ix);
        const __half2 m11h = __float2half2_rn(wy * wx);
        const int base = (y0 - ylo) * TSTR + x0;
#pragma unroll
        for (int wi = 0; wi < 4; ++wi) {
            const __half2* tw = tile + ((4 * h + wi) * TR) * TSTR;
            __half2 a = __hmul2(tw[base], m00h);
            a = __hfma2(tw[base + 1], m01h, a);
            a = __hfma2(tw[base + TSTR], m10h, a);
            a = __hfma2(tw[base + TSTR + 1], m11h, a);
            bw[wi] = __builtin_bit_cast(unsigned int, a);
        }
    } else {
        const TapS s = tap_setup(r, col, ky, kx, oy, ox, ylo, yhi);
        bw = tap_sample(s, h, tile, sg);
    }
    return bw;
}

// ---------- Kernel 2: deform conv (R20 structure) + single float2 offset load/tap ----------
__global__ __launch_bounds__(512, 4) void deform_kernel(
    const float* __restrict__ skip, const float2* __restrict__ offs2,
    const unsigned short* __restrict__ wA, float* __restrict__ out)
{
    __shared__ __half2 tile[TILE_W + TILE_PAD];   // 34336 B -> 4 blocks/CU

    const int tid = threadIdx.x;
    const int g = blockIdx.y & 3;
    const int b = blockIdx.y >> 2;
    const int r0  = blockIdx.x * ROWS;
    const int ylo = max(0, r0 - 2);
    const int yhi = min(Hn - 1, r0 + ROWS + 1);

    const float* sg = skip + (size_t)(b * Cn + g * Cg) * HW;

    for (int i = tid; i < TILE_W; i += 512) {
        const int w  = i / (TR * TSTR);
        const int re = i % (TR * TSTR);
        const int ty = re / TSTR;
        const int xx = re % TSTR;
        const int y  = ylo + ty;
        __half2 v = __floats2half2_rn(0.f, 0.f);
        if (xx < Wn && y <= yhi) {
            const float f0 = sg[(2 * w)     * HW + y * Wn + xx];
            const float f1 = sg[(2 * w + 1) * HW + y * Wn + xx];
            v = __floats2half2_rn(f0, f1);
        }
        tile[i] = v;
    }
    for (int i = TILE_W + tid; i < TILE_W + TILE_PAD; i += 512)
        tile[i] = __floats2half2_rn(0.f, 0.f);
    __syncthreads();

    const int wv   = tid >> 6;
    const int lane = tid & 63;
    const int p    = lane & 31;
    const int h    = lane >> 5;
    const int r    = r0 + (wv >> 1);
    const int jb   = (wv & 1) * 2;
    const int colA = jb * 32 + p;
    const int colB = colA + 32;

    const unsigned short* wAg = wA + (size_t)g * (KK * 512) + lane * 8;
    const float2* offpA = offs2 + (size_t)b * KK * HW + r * Wn + colA;
    const float2* offpB = offpA + 32;

    f32x16 accA, accB;
#pragma unroll
    for (int i = 0; i < 16; ++i) { accA[i] = 0.f; accB[i] = 0.f; }

#pragma unroll
    for (int t = 0; t < KK; ++t) {
        const int ky = t / 3, kx = t % 3;
        const float2 oA = offpA[(size_t)t * HW];   // one 8B load: (y,x)
        const float2 oB = offpB[(size_t)t * HW];

        const uint4v bwA = chunk_tap(r, colA, ky, kx, oA.x, oA.y, ylo, yhi, h, tile, sg);
        const uint4v bwB = chunk_tap(r, colB, ky, kx, oB.x, oB.y, ylo, yhi, h, tile, sg);

        const half8v afrag = *(const half8v*)(wAg + t * 512);
        accA = __builtin_amdgcn_mfma_f32_32x32x16_f16(afrag, __builtin_bit_cast(half8v, bwA), accA, 0, 0, 0);
        accB = __builtin_amdgcn_mfma_f32_32x32x16_f16(afrag, __builtin_bit_cast(half8v, bwB), accB, 0, 0, 0);
    }

    float* obA = out + (size_t)(b * Cn + g * Cg) * HW + r * Wn + colA;
#pragma unroll
    for (int reg = 0; reg < 8; ++reg) {
        const int o = (reg & 3) + 8 * (reg >> 2) + 4 * h;
        obA[o * HW]      = accA[reg];
        obA[o * HW + 32] = accB[reg];
    }
}

extern "C" void kernel_launch(void* const* d_in, const int* in_sizes, int n_in,
                              void* d_out, int out_size, void* d_ws, size_t ws_size,
                              hipStream_t stream) {
    const float* x        = (const float*)d_in[0];
    const float* skip     = (const float*)d_in[1];
    const float* offset_w = (const float*)d_in[2];
    const float* offset_b = (const float*)d_in[3];
    const float* deform_w = (const float*)d_in[4];
    float* out  = (float*)d_out;

    float2* offs2 = (float2*)d_ws;                                // 9.44 MB ([b][t][HW] pairs)
    unsigned short* wAo = (unsigned short*)((float*)d_ws + OFFS_ELEMS);  // 36.9 KB (bf16)
    unsigned short* wAd = wAo + WAO_ELEMS;                        // 36.9 KB (f16)

    hipLaunchKernelGGL(prep_w_kernel, dim3(8), dim3(256), 0, stream,
                       offset_w, deform_w, wAo, wAd);
    hipLaunchKernelGGL(offset_conv_kernel, dim3(Hn, Bn), dim3(256), 0, stream,
                       x, wAo, offset_b, offs2);
    hipLaunchKernelGGL(deform_kernel, dim3(Hn / ROWS, Bn * NG), dim3(512), 0, stream,
                       skip, offs2, wAd, out);
}